// Round 5
// baseline (337.658 us; speedup 1.0000x reference)
//
#include <hip/hip_runtime.h>
#include <cstdint>
#include <cmath>

// Problem constants
constexpr int TT   = 256;   // tokens
constexpr int HD   = 1024;  // hidden
constexpr int IDIM = 512;   // intermediate
constexpr int NE   = 32;    // experts
constexpr int NGRP = 8;
constexpr int TKG  = 4;
constexpr int TOPK = 8;
constexpr float RSCALE = 2.5f;

// Tiling: token tile 128 (MT=8 MFMA row-tiles), col tile 32, 128-thread blocks
constexpr int MT   = 8;
constexpr int BSTR = 40;   // LDS transposed-weight row stride in halves (80B: 2-way banks = free)

typedef float     f32x4 __attribute__((ext_vector_type(4)));
typedef _Float16  half8 __attribute__((ext_vector_type(8)));

// Workspace layout (bytes)
constexpr size_t WS_CNT = 0;                               // NE ints (zeroed)
constexpr size_t WS_TOK = 256;                             // NE*TT ints   (32 KB)
constexpr size_t WS_WL  = WS_TOK + (size_t)NE*TT*4;        // NE*TT floats (32 KB)
constexpr size_t WS_XE  = WS_WL  + (size_t)NE*TT*4;        // NE*TT*HD f16 (16 MB) gathered x rows
constexpr size_t WS_A   = WS_XE  + (size_t)NE*TT*HD*2;     // NE*TT*IDIM f16 (8 MB) silu(g)*u

// ---------------- Routing (unchanged from round 4) ----------------
__global__ __launch_bounds__(256) void k_route(
    const float* __restrict__ x, const float* __restrict__ gw,
    const float* __restrict__ bias, int* __restrict__ cnt,
    int* __restrict__ tok, float* __restrict__ wl)
{
    int t = blockIdx.x;
    int tid = threadIdx.x;
    int e2 = (tid & 15) * 2;
    int c  = tid >> 4;            // 0..15
    const float* xr = x + (size_t)t * HD;

    float a0 = 0.f, a1 = 0.f;
    int h0 = c * (HD / 16);
#pragma unroll 8
    for (int h = h0; h < h0 + HD / 16; ++h) {
        float xv = xr[h];
        float2 wv = *(const float2*)&gw[(size_t)h * NE + e2];
        a0 += xv * wv.x;
        a1 += xv * wv.y;
    }

    __shared__ float part[16][NE];
    part[c][e2]     = a0;
    part[c][e2 + 1] = a1;
    __syncthreads();

    __shared__ float sc[NE], sfc[NE];
    if (tid < NE) {
        float s = 0.f;
#pragma unroll
        for (int cc = 0; cc < 16; ++cc) s += part[cc][tid];
        float sig = 1.f / (1.f + expf(-s));
        sc[tid]  = sig;
        sfc[tid] = sig + bias[tid];
    }
    __syncthreads();

    if (tid == 0) {
        float gs[NGRP];
        for (int g = 0; g < NGRP; ++g) {
            float m1 = -3.0e38f, m2 = -3.0e38f;
            for (int j = 0; j < 4; ++j) {
                float v = sfc[4 * g + j];
                if (v > m1) { m2 = m1; m1 = v; } else if (v > m2) m2 = v;
            }
            gs[g] = m1 + m2;
        }
        bool gsel[NGRP];
        for (int g = 0; g < NGRP; ++g) gsel[g] = false;
        for (int r = 0; r < TKG; ++r) {
            int bi = -1; float bv = -3.0e38f;
            for (int g = 0; g < NGRP; ++g)
                if (!gsel[g] && gs[g] > bv) { bv = gs[g]; bi = g; }
            gsel[bi] = true;
        }
        float masked[NE];
        for (int i = 0; i < NE; ++i) masked[i] = gsel[i >> 2] ? sfc[i] : 0.0f;
        int   idx[TOPK]; float wv[TOPK]; float wsum = 0.f;
        for (int r = 0; r < TOPK; ++r) {
            int bi = -1; float bv = -3.0e38f;
            for (int i = 0; i < NE; ++i)
                if (masked[i] > bv) { bv = masked[i]; bi = i; }
            masked[bi] = -3.0e38f;
            idx[r] = bi; wv[r] = sc[bi]; wsum += wv[r];
        }
        float inv = RSCALE / (wsum + 1e-20f);
        for (int r = 0; r < TOPK; ++r) {
            int ee = idx[r];
            int pos = atomicAdd(&cnt[ee], 1);
            tok[(size_t)ee * TT + pos] = t;
            wl [(size_t)ee * TT + pos] = wv[r] * inv;
        }
    }
}

// ---------------- Pack: gather routed x rows to f16, per-expert ----------------
// block (e, sgrp): slots sgrp*8..sgrp*8+7. thread: slot = tid>>5, cols (tid&31)*32..+31
__global__ __launch_bounds__(256) void k_pack(
    const float* __restrict__ x, const int* __restrict__ cnt,
    const int* __restrict__ tok, _Float16* __restrict__ Xe)
{
    int e = blockIdx.x;
    int slot = blockIdx.y * 8 + (threadIdx.x >> 5);
    if (slot >= cnt[e]) return;
    int c0 = (threadIdx.x & 31) * 32;
    int t = tok[(size_t)e * TT + slot];
    const float* src = x + (size_t)t * HD + c0;
    _Float16* dst = Xe + ((size_t)e * TT + slot) * HD + c0;
#pragma unroll
    for (int j = 0; j < 4; ++j) {
        f32x4 v0 = *(const f32x4*)(src + j * 8);
        f32x4 v1 = *(const f32x4*)(src + j * 8 + 4);
        half8 h;
        h[0] = (_Float16)v0.x; h[1] = (_Float16)v0.y; h[2] = (_Float16)v0.z; h[3] = (_Float16)v0.w;
        h[4] = (_Float16)v1.x; h[5] = (_Float16)v1.y; h[6] = (_Float16)v1.z; h[7] = (_Float16)v1.w;
        *(half8*)(dst + j * 8) = h;
    }
}

// ---- shared helpers for the staged GEMMs ----
struct PF8 { float v[8]; };

__device__ __forceinline__ void issue8(PF8& r, const float* p, int tile, int rowstride) {
    const float* q = p + (size_t)tile * 32 * rowstride;
#pragma unroll
    for (int j = 0; j < 8; ++j) r.v[j] = q[(size_t)j * rowstride];
}
__device__ __forceinline__ void stage8(_Float16* B, const PF8& r, int sn, int skg) {
    half8 h;
#pragma unroll
    for (int j = 0; j < 8; ++j) h[j] = (_Float16)r.v[j];
    *(half8*)&B[sn * BSTR + skg * 8] = h;
}

// ---------------- Gate/Up: A = silu(Xe Wg) * (Xe Wu), per expert ----------------
// grid (NE*2, IDIM/32); block 128 (2 waves); tile 128 tokens x 32 cols; K=1024, KS=32
__global__ __launch_bounds__(128) void k_gateup(
    const _Float16* __restrict__ Xe, const float* __restrict__ Wg,
    const float* __restrict__ Wu, const int* __restrict__ cnt,
    _Float16* __restrict__ A)
{
    int e = blockIdx.x >> 1, ttile = blockIdx.x & 1;
    int n_e = cnt[e];
    int row0 = ttile * 128;
    if (row0 >= n_e) return;
    int mtc = (min(128, n_e - row0) + 15) >> 4;
    int i0 = blockIdx.y * 32;
    int tid = threadIdx.x;
    int lane = tid & 63, w = tid >> 6;       // wave 0/1
    int q = lane >> 4;                       // quad 0..3
    int m16 = lane & 15;

    __shared__ __align__(16) _Float16 Bg0[32 * BSTR], Bu0[32 * BSTR];
    __shared__ __align__(16) _Float16 Bg1[32 * BSTR], Bu1[32 * BSTR];

    // A-row base pointers (packed f16 rows; rows beyond n_e hold garbage, results discarded)
    const _Float16* abase[MT];
#pragma unroll
    for (int mt = 0; mt < MT; ++mt)
        abase[mt] = Xe + ((size_t)e * TT + row0 + mt * 16 + m16) * HD;

    // staging: thread owns col sn (0..31) and k-group skg (0..3 -> rows skg*8..+7)
    int sn = tid & 31, skg = tid >> 5;
    const float* gptr = Wg + ((size_t)e * HD + skg * 8) * IDIM + i0 + sn;
    const float* uptr = Wu + ((size_t)e * HD + skg * 8) * IDIM + i0 + sn;

    f32x4 accG[MT], accU[MT];
#pragma unroll
    for (int mt = 0; mt < MT; ++mt) {
        accG[mt] = (f32x4){0.f, 0.f, 0.f, 0.f};
        accU[mt] = (f32x4){0.f, 0.f, 0.f, 0.f};
    }

    int cfrag = w * 16 + m16;          // column within 32-tile this lane computes
    int koff = q * 8;

    PF8 rg0, ru0, rg1, ru1;
    constexpr int NK = HD / 32;        // 32

    // preamble: tile0 -> LDS buf0; tile1 in flight in reg set1
    issue8(rg0, gptr, 0, IDIM); issue8(ru0, uptr, 0, IDIM);
    stage8(Bg0, rg0, sn, skg);  stage8(Bu0, ru0, sn, skg);
    issue8(rg1, gptr, 1, IDIM); issue8(ru1, uptr, 1, IDIM);
    __syncthreads();

#define GU_STEP(BG, BU, KS)                                                      \
    {                                                                            \
        half8 bg = *(const half8*)&BG[cfrag * BSTR + koff];                      \
        half8 bu = *(const half8*)&BU[cfrag * BSTR + koff];                      \
        _Pragma("unroll")                                                        \
        for (int mt = 0; mt < MT; ++mt) {                                        \
            if (mt < mtc) {                                                      \
                half8 af = *(const half8*)(abase[mt] + (KS) * 32 + koff);        \
                accG[mt] = __builtin_amdgcn_mfma_f32_16x16x32_f16(af, bg, accG[mt], 0, 0, 0); \
                accU[mt] = __builtin_amdgcn_mfma_f32_16x16x32_f16(af, bu, accU[mt], 0, 0, 0); \
            }                                                                    \
        }                                                                        \
    }

    for (int ks = 0; ks < NK; ks += 2) {
        if (ks + 2 < NK) { issue8(rg0, gptr, ks + 2, IDIM); issue8(ru0, uptr, ks + 2, IDIM); }
        GU_STEP(Bg0, Bu0, ks)
        if (ks + 1 < NK) { stage8(Bg1, rg1, sn, skg); stage8(Bu1, ru1, sn, skg); }
        __syncthreads();
        if (ks + 1 < NK) {
            if (ks + 3 < NK) { issue8(rg1, gptr, ks + 3, IDIM); issue8(ru1, uptr, ks + 3, IDIM); }
            GU_STEP(Bg1, Bu1, ks + 1)
            if (ks + 2 < NK) { stage8(Bg0, rg0, sn, skg); stage8(Bu0, ru0, sn, skg); }
            __syncthreads();
        }
    }
#undef GU_STEP

    int col = i0 + cfrag;
#pragma unroll
    for (int mt = 0; mt < MT; ++mt) {
        if (mt < mtc) {
#pragma unroll
            for (int r = 0; r < 4; ++r) {
                int row = row0 + mt * 16 + q * 4 + r;
                float g = accG[mt][r], u = accU[mt][r];
                float a = (g / (1.f + expf(-g))) * u;
                A[((size_t)e * TT + row) * IDIM + col] = (_Float16)a;
            }
        }
    }
}

// ---------------- Down: out += w * (A Wd), per expert ----------------
// grid (NE*2, HD/32); block 128; tile 128 tokens x 32 cols; K=512, KS=32
__global__ __launch_bounds__(128) void k_down(
    const _Float16* __restrict__ A, const float* __restrict__ Wd,
    const int* __restrict__ cnt, const int* __restrict__ tok,
    const float* __restrict__ wl, float* __restrict__ outf)
{
    int e = blockIdx.x >> 1, ttile = blockIdx.x & 1;
    int n_e = cnt[e];
    int row0 = ttile * 128;
    if (row0 >= n_e) return;
    int mtc = (min(128, n_e - row0) + 15) >> 4;
    int h0 = blockIdx.y * 32;
    int tid = threadIdx.x;
    int lane = tid & 63, w = tid >> 6;
    int q = lane >> 4;
    int m16 = lane & 15;

    __shared__ __align__(16) _Float16 Bd0[32 * BSTR], Bd1[32 * BSTR];

    const _Float16* abase[MT];
#pragma unroll
    for (int mt = 0; mt < MT; ++mt)
        abase[mt] = A + ((size_t)e * TT + row0 + mt * 16 + m16) * IDIM;

    int sn = tid & 31, skg = tid >> 5;
    const float* dptr = Wd + ((size_t)e * IDIM + skg * 8) * HD + h0 + sn;

    f32x4 acc[MT];
#pragma unroll
    for (int mt = 0; mt < MT; ++mt) acc[mt] = (f32x4){0.f, 0.f, 0.f, 0.f};

    int cfrag = w * 16 + m16;
    int koff = q * 8;

    PF8 rd0, rd1;
    constexpr int NK = IDIM / 32;      // 16

    issue8(rd0, dptr, 0, HD);
    stage8(Bd0, rd0, sn, skg);
    issue8(rd1, dptr, 1, HD);
    __syncthreads();

#define DN_STEP(BD, KS)                                                          \
    {                                                                            \
        half8 bd = *(const half8*)&BD[cfrag * BSTR + koff];                      \
        _Pragma("unroll")                                                        \
        for (int mt = 0; mt < MT; ++mt) {                                        \
            if (mt < mtc) {                                                      \
                half8 af = *(const half8*)(abase[mt] + (KS) * 32 + koff);        \
                acc[mt] = __builtin_amdgcn_mfma_f32_16x16x32_f16(af, bd, acc[mt], 0, 0, 0); \
            }                                                                    \
        }                                                                        \
    }

    for (int ks = 0; ks < NK; ks += 2) {
        if (ks + 2 < NK) issue8(rd0, dptr, ks + 2, HD);
        DN_STEP(Bd0, ks)
        if (ks + 1 < NK) stage8(Bd1, rd1, sn, skg);
        __syncthreads();
        if (ks + 1 < NK) {
            if (ks + 3 < NK) issue8(rd1, dptr, ks + 3, HD);
            DN_STEP(Bd1, ks + 1)
            if (ks + 2 < NK) stage8(Bd0, rd0, sn, skg);
            __syncthreads();
        }
    }
#undef DN_STEP

    int col = h0 + cfrag;
#pragma unroll
    for (int mt = 0; mt < MT; ++mt) {
        if (mt < mtc) {
#pragma unroll
            for (int r = 0; r < 4; ++r) {
                int slot = row0 + mt * 16 + q * 4 + r;
                if (slot < n_e) {
                    int t  = tok[(size_t)e * TT + slot];
                    float wt = wl[(size_t)e * TT + slot];
                    atomicAdd(&outf[(size_t)t * HD + col], wt * acc[mt][r]);
                }
            }
        }
    }
}

extern "C" void kernel_launch(void* const* d_in, const int* in_sizes, int n_in,
                              void* d_out, int out_size, void* d_ws, size_t ws_size,
                              hipStream_t stream) {
    const float* x    = (const float*)d_in[0];
    const float* gw   = (const float*)d_in[1];
    const float* bias = (const float*)d_in[2];
    const float* Wg   = (const float*)d_in[3];
    const float* Wu   = (const float*)d_in[4];
    const float* Wd   = (const float*)d_in[5];
    float* out = (float*)d_out;   // reference output dtype is float32

    char* ws = (char*)d_ws;
    int*      cnt = (int*)(ws + WS_CNT);
    int*      tok = (int*)(ws + WS_TOK);
    float*    wl  = (float*)(ws + WS_WL);
    _Float16* Xe  = (_Float16*)(ws + WS_XE);
    _Float16* A   = (_Float16*)(ws + WS_A);

    hipMemsetAsync(ws, 0, 256, stream);                       // expert counters
    hipMemsetAsync(out, 0, (size_t)TT * HD * 4, stream);      // f32 output accumulator

    k_route<<<TT, 256, 0, stream>>>(x, gw, bias, cnt, tok, wl);
    k_pack<<<dim3(NE, TT / 8), 256, 0, stream>>>(x, cnt, tok, Xe);
    k_gateup<<<dim3(NE * 2, IDIM / 32), 128, 0, stream>>>(Xe, Wg, Wu, cnt, A);
    k_down<<<dim3(NE * 2, HD / 32), 128, 0, stream>>>(A, Wd, cnt, tok, wl, out);
}

// Round 6
// 315.005 us; speedup vs baseline: 1.0719x; 1.0719x over previous
//
#include <hip/hip_runtime.h>
#include <cstdint>
#include <cmath>

// Problem constants
constexpr int TT   = 256;   // tokens
constexpr int HD   = 1024;  // hidden
constexpr int IDIM = 512;   // intermediate
constexpr int NE   = 32;    // experts
constexpr int NGRP = 8;
constexpr int TKG  = 4;
constexpr int TOPK = 8;
constexpr float RSCALE = 2.5f;

constexpr int NSX  = HD / 32;     // 32 k-slabs in Xe
constexpr int NSA  = IDIM / 32;   // 16 k-slabs in A
constexpr int SLAB = 16 * 64 * 8; // halves per (expert, slab): 16 mt-tiles x 64 lanes x 8
constexpr int BSTR = 40;          // LDS weight-tile row stride (halves)

typedef float    f32x4 __attribute__((ext_vector_type(4)));
typedef _Float16 half8 __attribute__((ext_vector_type(8)));

// Workspace layout (bytes)
constexpr size_t WS_CNT = 0;                              // NE ints (zeroed)
constexpr size_t WS_TOK = 256;                            // NE*TT ints
constexpr size_t WS_WL  = WS_TOK + (size_t)NE * TT * 4;   // NE*TT floats
constexpr size_t WS_XE  = WS_WL  + (size_t)NE * TT * 4;   // NE*NSX*SLAB f16 (16 MB), frag-swizzled x
constexpr size_t WS_A   = WS_XE  + (size_t)NE * NSX * SLAB * 2; // NE*NSA*SLAB f16 (8 MB)

// ---------------- Routing (unchanged from round 4) ----------------
__global__ __launch_bounds__(256) void k_route(
    const float* __restrict__ x, const float* __restrict__ gw,
    const float* __restrict__ bias, int* __restrict__ cnt,
    int* __restrict__ tok, float* __restrict__ wl)
{
    int t = blockIdx.x;
    int tid = threadIdx.x;
    int e2 = (tid & 15) * 2;
    int c  = tid >> 4;
    const float* xr = x + (size_t)t * HD;

    float a0 = 0.f, a1 = 0.f;
    int h0 = c * (HD / 16);
#pragma unroll 8
    for (int h = h0; h < h0 + HD / 16; ++h) {
        float xv = xr[h];
        float2 wv = *(const float2*)&gw[(size_t)h * NE + e2];
        a0 += xv * wv.x;
        a1 += xv * wv.y;
    }

    __shared__ float part[16][NE];
    part[c][e2]     = a0;
    part[c][e2 + 1] = a1;
    __syncthreads();

    __shared__ float sc[NE], sfc[NE];
    if (tid < NE) {
        float s = 0.f;
#pragma unroll
        for (int cc = 0; cc < 16; ++cc) s += part[cc][tid];
        float sig = 1.f / (1.f + expf(-s));
        sc[tid]  = sig;
        sfc[tid] = sig + bias[tid];
    }
    __syncthreads();

    if (tid == 0) {
        float gs[NGRP];
        for (int g = 0; g < NGRP; ++g) {
            float m1 = -3.0e38f, m2 = -3.0e38f;
            for (int j = 0; j < 4; ++j) {
                float v = sfc[4 * g + j];
                if (v > m1) { m2 = m1; m1 = v; } else if (v > m2) m2 = v;
            }
            gs[g] = m1 + m2;
        }
        bool gsel[NGRP];
        for (int g = 0; g < NGRP; ++g) gsel[g] = false;
        for (int r = 0; r < TKG; ++r) {
            int bi = -1; float bv = -3.0e38f;
            for (int g = 0; g < NGRP; ++g)
                if (!gsel[g] && gs[g] > bv) { bv = gs[g]; bi = g; }
            gsel[bi] = true;
        }
        float masked[NE];
        for (int i = 0; i < NE; ++i) masked[i] = gsel[i >> 2] ? sfc[i] : 0.0f;
        int   idx[TOPK]; float wv[TOPK]; float wsum = 0.f;
        for (int r = 0; r < TOPK; ++r) {
            int bi = -1; float bv = -3.0e38f;
            for (int i = 0; i < NE; ++i)
                if (masked[i] > bv) { bv = masked[i]; bi = i; }
            masked[bi] = -3.0e38f;
            idx[r] = bi; wv[r] = sc[bi]; wsum += wv[r];
        }
        float inv = RSCALE / (wsum + 1e-20f);
        for (int r = 0; r < TOPK; ++r) {
            int ee = idx[r];
            int pos = atomicAdd(&cnt[ee], 1);
            tok[(size_t)ee * TT + pos] = t;
            wl [(size_t)ee * TT + pos] = wv[r] * inv;
        }
    }
}

// ---------------- Pack: gather x rows into MFMA-A-fragment slabs ----------------
// Xe[(e,slab)][mt][lane][j] = x[tok[e][mt*16+(lane&15)]][slab*32+(lane>>4)*8+j], f16.
__global__ __launch_bounds__(256) void k_pack(
    const float* __restrict__ x, const int* __restrict__ cnt,
    const int* __restrict__ tok, _Float16* __restrict__ Xe)
{
    int e = blockIdx.x, s = blockIdx.y;
    int n_e = cnt[e];
    if (n_e == 0) return;
    int tid = threadIdx.x, w = tid >> 6, lane = tid & 63;
    int m16 = lane & 15, q = lane >> 4;
    _Float16* base = Xe + ((size_t)e * NSX + s) * SLAB;
#pragma unroll
    for (int k = 0; k < 4; ++k) {
        int mt = w + k * 4;
        int slot = mt * 16 + m16;
        if (slot >= n_e) slot = n_e - 1;   // clamp: dup of last row (finite garbage)
        int t = tok[e * TT + slot];
        const float* src = x + (size_t)t * HD + s * 32 + q * 8;
        f32x4 v0 = *(const f32x4*)src;
        f32x4 v1 = *(const f32x4*)(src + 4);
        half8 h;
        h[0] = (_Float16)v0.x; h[1] = (_Float16)v0.y; h[2] = (_Float16)v0.z; h[3] = (_Float16)v0.w;
        h[4] = (_Float16)v1.x; h[5] = (_Float16)v1.y; h[6] = (_Float16)v1.z; h[7] = (_Float16)v1.w;
        *(half8*)(base + ((size_t)mt * 64 + lane) * 8) = h;
    }
}

// ---- pipeline macros (issue order == consume order; no barriers) ----
#define ISSUE_A(KS, AF, ABASE)                                                  \
    { const _Float16* a_ = (ABASE) + (size_t)(KS) * SLAB;                       \
      _Pragma("unroll")                                                         \
      for (int mt_ = 0; mt_ < 8; ++mt_) AF[mt_] = *(const half8*)(a_ + mt_ * 512); }

#define ISSUE_W1(KS, WR, P0, STRIDE)                                            \
    { const float* w_ = (P0) + (size_t)(KS) * 32 * (STRIDE);                    \
      _Pragma("unroll")                                                         \
      for (int j_ = 0; j_ < 8; ++j_) WR[j_] = w_[(size_t)j_ * (STRIDE)]; }

#define STAGE_W1(WR, B, P)                                                      \
    { half8 h_;                                                                 \
      _Pragma("unroll")                                                         \
      for (int j_ = 0; j_ < 8; ++j_) h_[j_] = (_Float16)WR[j_];                 \
      *(half8*)&B[P][sn * BSTR + skg * 8] = h_; }

// ---------------- Gate/Up ----------------
// grid (NE*2, IDIM/16); 64-thread (1-wave) blocks; tile 128 tokens x 16 cols.
__global__ __launch_bounds__(64) void k_gateup(
    const _Float16* __restrict__ Xe, const float* __restrict__ Wg,
    const float* __restrict__ Wu, const int* __restrict__ cnt,
    _Float16* __restrict__ A)
{
    int e = blockIdx.x >> 1, ttile = blockIdx.x & 1;
    int n_e = cnt[e];
    if (ttile * 128 >= n_e) return;
    int mtbase = ttile * 8;
    int i0 = blockIdx.y * 16;
    int lane = threadIdx.x;
    int m16 = lane & 15, q = lane >> 4;
    int sn = m16, skg = q;

    __shared__ __align__(16) _Float16 BG[2][16 * BSTR], BU[2][16 * BSTR];

    const _Float16* abase = Xe + (size_t)e * NSX * SLAB + ((size_t)mtbase * 64 + lane) * 8;
    const float* gp = Wg + ((size_t)e * HD + skg * 8) * IDIM + i0 + sn;
    const float* up = Wu + ((size_t)e * HD + skg * 8) * IDIM + i0 + sn;

    f32x4 accG[8], accU[8];
#pragma unroll
    for (int mt = 0; mt < 8; ++mt) {
        accG[mt] = (f32x4){0.f, 0.f, 0.f, 0.f};
        accU[mt] = (f32x4){0.f, 0.f, 0.f, 0.f};
    }

    half8 af0[8], af1[8];
    float wg0[8], wu0[8], wg1[8], wu1[8];

#define GU_COMPUTE(AF, P)                                                        \
    { half8 bg_ = *(const half8*)&BG[P][m16 * BSTR + q * 8];                     \
      half8 bu_ = *(const half8*)&BU[P][m16 * BSTR + q * 8];                     \
      _Pragma("unroll")                                                          \
      for (int mt_ = 0; mt_ < 8; ++mt_) {                                        \
        accG[mt_] = __builtin_amdgcn_mfma_f32_16x16x32_f16(AF[mt_], bg_, accG[mt_], 0, 0, 0); \
        accU[mt_] = __builtin_amdgcn_mfma_f32_16x16x32_f16(AF[mt_], bu_, accU[mt_], 0, 0, 0); \
      } }

    constexpr int NK = HD / 32;   // 32
    ISSUE_A(0, af0, abase) ISSUE_W1(0, wg0, gp, IDIM) ISSUE_W1(0, wu0, up, IDIM)
    ISSUE_A(1, af1, abase) ISSUE_W1(1, wg1, gp, IDIM) ISSUE_W1(1, wu1, up, IDIM)
    STAGE_W1(wg0, BG, 0) STAGE_W1(wu0, BU, 0)

    for (int ks = 0; ks < NK; ks += 2) {
        GU_COMPUTE(af0, 0)
        if (ks + 2 < NK) {
            ISSUE_A(ks + 2, af0, abase)
            ISSUE_W1(ks + 2, wg0, gp, IDIM) ISSUE_W1(ks + 2, wu0, up, IDIM)
        }
        STAGE_W1(wg1, BG, 1) STAGE_W1(wu1, BU, 1)
        GU_COMPUTE(af1, 1)
        if (ks + 3 < NK) {
            ISSUE_A(ks + 3, af1, abase)
            ISSUE_W1(ks + 3, wg1, gp, IDIM) ISSUE_W1(ks + 3, wu1, up, IDIM)
        }
        if (ks + 2 < NK) { STAGE_W1(wg0, BG, 0) STAGE_W1(wu0, BU, 0) }
    }
#undef GU_COMPUTE

    // store silu(g)*u into A in A-fragment slab order (for k_down's A-operand)
    _Float16* aout = A + ((size_t)e * NSA + (blockIdx.y >> 1)) * SLAB;
    int cj   = m16 & 7;
    int lsub = ((blockIdx.y * 2 + (m16 >> 3)) & 3) * 16;
#pragma unroll
    for (int mt = 0; mt < 8; ++mt) {
#pragma unroll
        for (int r = 0; r < 4; ++r) {
            float g = accG[mt][r], u = accU[mt][r];
            float a = (g / (1.f + expf(-g))) * u;
            int lp = (q * 4 + r) + lsub;
            aout[((size_t)(mtbase + mt) * 64 + lp) * 8 + cj] = (_Float16)a;
        }
    }
}

// ---------------- Down ----------------
// grid (NE*2, HD/16); 64-thread blocks; tile 128 tokens x 16 cols.
__global__ __launch_bounds__(64) void k_down(
    const _Float16* __restrict__ A, const float* __restrict__ Wd,
    const int* __restrict__ cnt, const int* __restrict__ tok,
    const float* __restrict__ wl, float* __restrict__ outf)
{
    int e = blockIdx.x >> 1, ttile = blockIdx.x & 1;
    int n_e = cnt[e];
    if (ttile * 128 >= n_e) return;
    int mtbase = ttile * 8;
    int h0 = blockIdx.y * 16;
    int lane = threadIdx.x;
    int m16 = lane & 15, q = lane >> 4;
    int sn = m16, skg = q;

    __shared__ __align__(16) _Float16 BD[2][16 * BSTR];

    const _Float16* abase = A + (size_t)e * NSA * SLAB + ((size_t)mtbase * 64 + lane) * 8;
    const float* dp = Wd + ((size_t)e * IDIM + skg * 8) * HD + h0 + sn;

    f32x4 acc[8];
#pragma unroll
    for (int mt = 0; mt < 8; ++mt) acc[mt] = (f32x4){0.f, 0.f, 0.f, 0.f};

    half8 af0[8], af1[8];
    float wd0[8], wd1[8];

#define DN_COMPUTE(AF, P)                                                        \
    { half8 bd_ = *(const half8*)&BD[P][m16 * BSTR + q * 8];                     \
      _Pragma("unroll")                                                          \
      for (int mt_ = 0; mt_ < 8; ++mt_)                                          \
        acc[mt_] = __builtin_amdgcn_mfma_f32_16x16x32_f16(AF[mt_], bd_, acc[mt_], 0, 0, 0); }

    constexpr int NK = IDIM / 32;  // 16
    ISSUE_A(0, af0, abase) ISSUE_W1(0, wd0, dp, HD)
    ISSUE_A(1, af1, abase) ISSUE_W1(1, wd1, dp, HD)
    STAGE_W1(wd0, BD, 0)

    for (int ks = 0; ks < NK; ks += 2) {
        DN_COMPUTE(af0, 0)
        if (ks + 2 < NK) { ISSUE_A(ks + 2, af0, abase) ISSUE_W1(ks + 2, wd0, dp, HD) }
        STAGE_W1(wd1, BD, 1)
        DN_COMPUTE(af1, 1)
        if (ks + 3 < NK) { ISSUE_A(ks + 3, af1, abase) ISSUE_W1(ks + 3, wd1, dp, HD) }
        if (ks + 2 < NK) STAGE_W1(wd0, BD, 0)
    }
#undef DN_COMPUTE

    int col = h0 + m16;
#pragma unroll
    for (int mt = 0; mt < 8; ++mt) {
#pragma unroll
        for (int r = 0; r < 4; ++r) {
            int slot = ttile * 128 + mt * 16 + q * 4 + r;
            if (slot < n_e) {
                int t   = tok[(size_t)e * TT + slot];
                float wt = wl[(size_t)e * TT + slot];
                atomicAdd(&outf[(size_t)t * HD + col], wt * acc[mt][r]);
            }
        }
    }
}

extern "C" void kernel_launch(void* const* d_in, const int* in_sizes, int n_in,
                              void* d_out, int out_size, void* d_ws, size_t ws_size,
                              hipStream_t stream) {
    const float* x    = (const float*)d_in[0];
    const float* gw   = (const float*)d_in[1];
    const float* bias = (const float*)d_in[2];
    const float* Wg   = (const float*)d_in[3];
    const float* Wu   = (const float*)d_in[4];
    const float* Wd   = (const float*)d_in[5];
    float* out = (float*)d_out;   // reference output dtype is float32

    char* ws = (char*)d_ws;
    int*      cnt = (int*)(ws + WS_CNT);
    int*      tok = (int*)(ws + WS_TOK);
    float*    wl  = (float*)(ws + WS_WL);
    _Float16* Xe  = (_Float16*)(ws + WS_XE);
    _Float16* A   = (_Float16*)(ws + WS_A);

    hipMemsetAsync(ws, 0, 256, stream);                       // expert counters
    hipMemsetAsync(out, 0, (size_t)TT * HD * 4, stream);      // f32 output accumulator

    k_route<<<TT, 256, 0, stream>>>(x, gw, bias, cnt, tok, wl);
    k_pack<<<dim3(NE, NSX), 256, 0, stream>>>(x, cnt, tok, Xe);
    k_gateup<<<dim3(NE * 2, IDIM / 16), 64, 0, stream>>>(Xe, Wg, Wu, cnt, A);
    k_down<<<dim3(NE * 2, HD / 16), 64, 0, stream>>>(A, Wd, cnt, tok, wl, out);
}